// Round 13
// baseline (519.015 us; speedup 1.0000x reference)
//
#include <hip/hip_runtime.h>
#include <hip/hip_bf16.h>
#include <math.h>

#define NN 50000
#define NE 800000
#define NGRAPH 128
#define HEADS 8
#define CH 32
#define HID 256
#define NEG_SLOPE 0.2f

typedef __attribute__((ext_vector_type(8))) short short8;
typedef __attribute__((ext_vector_type(4))) short short4v;
typedef __attribute__((ext_vector_type(4))) float v4f;

__device__ inline float bflo(unsigned u) { return __builtin_bit_cast(float, u << 16); }
__device__ inline float bfhi(unsigned u) { return __builtin_bit_cast(float, u & 0xFFFF0000u); }
__device__ inline float bf2f(short s) {
    return __builtin_bit_cast(float, ((unsigned)(unsigned short)s) << 16);
}
__device__ inline short f2bf(float f) {
    __hip_bfloat16 b = __float2bfloat16(f);
    return __builtin_bit_cast(short, b);
}
// monotonic float<->uint order-preserving map (for atomicMax on floats)
__device__ inline unsigned fkey(float f) {
    unsigned u = __builtin_bit_cast(unsigned, f);
    return (u & 0x80000000u) ? ~u : (u | 0x80000000u);
}
__device__ inline float unfkey(unsigned u) {
    unsigned v = (u & 0x80000000u) ? (u & 0x7FFFFFFFu) : ~u;
    return __builtin_bit_cast(float, v);
}

// ---------------- fused prep: W swizzle-convert (blocks 0..767) + edge count (rest) ----------------
// counts[] pre-zeroed by memset; self-loop handled as +1 inside the scans.

__global__ void prep_kernel(const float* __restrict__ W0, const float* __restrict__ Wh,
                            short* __restrict__ Wt0, short* __restrict__ Wt1,
                            short* __restrict__ Wt2,
                            const int* __restrict__ dst, int* __restrict__ counts, int e) {
    int b = blockIdx.x;
    if (b < 768) {
        int which = b >> 8;
        int n = b & 255;
        const float* W = (which == 0) ? W0 : (which == 1) ? Wh : Wh + 256 * 256;
        short* Wt = (which == 0) ? Wt0 : (which == 1) ? Wt1 : Wt2;
        int K = (which == 0) ? 128 : 256;
        int tile16 = n >> 4, l16 = n & 15;
        int KC = K >> 5;
        for (int k = threadIdx.x; k < K; k += blockDim.x) {
            int kc = k >> 5, quad = (k & 31) >> 3, j = k & 7;
            int lane = quad * 16 + l16;
            Wt[(size_t)(((tile16 * KC + kc) * 64 + lane)) * 8 + j] = f2bf(W[(size_t)k * 256 + n]);
        }
    } else {
        int i = (b - 768) * 256 + threadIdx.x;
        if (i < e) atomicAdd(&counts[dst[i]], 1);
    }
}

__device__ inline int wave_incl_scan(int v, int lane) {
#pragma unroll
    for (int off = 1; off < 64; off <<= 1) {
        int u = __shfl_up(v, off);
        if (lane >= off) v += u;
    }
    return v;
}

__global__ __launch_bounds__(1024) void scan_part_kernel(const int* __restrict__ counts,
                                                         int* partial, int n) {
    int i = blockIdx.x * 1024 + threadIdx.x;
    int v = (i < n) ? counts[i] + 1 : 0;   // +1 self-loop
    int lane = threadIdx.x & 63, w = threadIdx.x >> 6;
    __shared__ int ws[16];
    int sv = wave_incl_scan(v, lane);
    if (lane == 63) ws[w] = sv;
    __syncthreads();
    if (threadIdx.x == 0) {
        int tot = 0;
#pragma unroll
        for (int j = 0; j < 16; j++) tot += ws[j];
        partial[blockIdx.x] = tot;
    }
}

// final scan; block-offset computed inline from partials (nb <= 64)
__global__ __launch_bounds__(1024) void scan_final_kernel(const int* __restrict__ counts,
                                                          const int* __restrict__ partial,
                                                          int* row_ptr, int* cursor, int n) {
    __shared__ int ws[17];
    __shared__ int s_off;
    int i = blockIdx.x * 1024 + threadIdx.x;
    int v = (i < n) ? counts[i] + 1 : 0;   // +1 self-loop
    int lane = threadIdx.x & 63, w = threadIdx.x >> 6;
    if (threadIdx.x < 64) {
        int pv = ((int)threadIdx.x < (int)blockIdx.x) ? partial[threadIdx.x] : 0;
#pragma unroll
        for (int off = 1; off < 64; off <<= 1) pv += __shfl_xor(pv, off);
        if (threadIdx.x == 0) s_off = pv;
    }
    int sv = wave_incl_scan(v, lane);
    if (lane == 63) ws[w] = sv;
    __syncthreads();
    if (w == 0) {
        int t = (lane < 16) ? ws[lane] : 0;
        int ts = wave_incl_scan(t, lane);
        if (lane < 16) ws[lane] = ts;
    }
    __syncthreads();
    int waveBase = (w > 0) ? ws[w - 1] : 0;
    int off = s_off;
    int incl = waveBase + sv;
    if (i < n) {
        int ex = off + incl - v;
        row_ptr[i] = ex;
        cursor[i] = ex;
        if (i == n - 1) row_ptr[n] = off + incl;
    }
}

// ---------------- MFMA GEMM: H[M,256](bf16) = A[M,K] @ W (swizzled bf16) ----------------
// block = 128 rows x 256 cols, 4 waves; wave = 64 rows x 128 cols (4x8 mfma tiles).
// 32 MFMA per 8 B-loads (4:1); grid 391 <= 512 resident (no tail rounds).
// A staged coalesced in LDS (union with epilogue tile); B coalesced via swizzle.

#define EP_STRIDE 144

template <int K, bool AF32>
__global__ __launch_bounds__(256, 2) void gemm_mfma_kernel(const void* __restrict__ Ap,
                                                           const short* __restrict__ Wt,
                                                           short* __restrict__ H,
                                                           int M) {
    constexpr int KC = K >> 5;
    constexpr int ASTRIDE = K + 8;
    union LdsU {
        short a[128][ASTRIDE];
        short ep[4][64][EP_STRIDE];
    };
    __shared__ LdsU lds;

    int t = threadIdx.x;
    int w = t >> 6;
    int lane = t & 63;
    int quad = lane >> 4, l16 = lane & 15;
    int wm = w & 1, wn = w >> 1;
    int m0 = blockIdx.x * 128;
    int m_base = m0 + wm * 64;
    int n_base = wn * 128;

    // ---- stage A[128][K] into LDS, fully coalesced global reads ----
    if constexpr (AF32) {
        constexpr int C4 = K / 4;
        const float* A = (const float*)Ap;
        for (int s = t; s < 128 * C4; s += 256) {
            int row = s / C4;
            int c4 = s % C4;
            int gr = m0 + row; if (gr >= M) gr = M - 1;
            float4 v = *(const float4*)&A[(size_t)gr * K + c4 * 4];
            union { short4v s4; __hip_bfloat162 b[2]; } p;
            p.b[0] = __float22bfloat162_rn(make_float2(v.x, v.y));
            p.b[1] = __float22bfloat162_rn(make_float2(v.z, v.w));
            *(short4v*)&lds.a[row][c4 * 4] = p.s4;
        }
    } else {
        constexpr int C8 = K / 8;
        const short* A = (const short*)Ap;
        for (int s = t; s < 128 * C8; s += 256) {
            int row = s / C8;
            int c8 = s % C8;
            int gr = m0 + row; if (gr >= M) gr = M - 1;
            *(short8*)&lds.a[row][c8 * 8] = *(const short8*)&A[(size_t)gr * K + c8 * 8];
        }
    }
    __syncthreads();

    v4f acc[4][8] = {};
    // swizzled B base for this wave: tiles wn*8 .. wn*8+7
    const short* bw = Wt + ((size_t)(wn * 8) * KC * 64 + lane) * 8;

#pragma unroll
    for (int kc = 0; kc < KC; kc++) {
        short8 b_frag[8];
#pragma unroll
        for (int nj = 0; nj < 8; nj++)
            b_frag[nj] = *(const short8*)(bw + (size_t)(nj * KC + kc) * 64 * 8);
        short8 a_frag[4];
#pragma unroll
        for (int mi = 0; mi < 4; mi++)
            a_frag[mi] = *(const short8*)&lds.a[wm * 64 + mi * 16 + l16][kc * 32 + quad * 8];
#pragma unroll
        for (int mi = 0; mi < 4; mi++)
#pragma unroll
            for (int nj = 0; nj < 8; nj++)
                acc[mi][nj] = __builtin_amdgcn_mfma_f32_16x16x32_bf16(a_frag[mi], b_frag[nj],
                                                                      acc[mi][nj], 0, 0, 0);
    }
    __syncthreads();   // all lds.a reads complete before ep overwrite

#pragma unroll
    for (int mi = 0; mi < 4; mi++)
#pragma unroll
        for (int r = 0; r < 4; r++) {
            int rl = mi * 16 + quad * 4 + r;
#pragma unroll
            for (int nj = 0; nj < 8; nj++)
                lds.ep[w][rl][nj * 16 + l16] = f2bf(acc[mi][nj][r]);
        }
    __syncthreads();

    int rq = lane >> 4;
#pragma unroll
    for (int it = 0; it < 16; it++) {
        int rl = it * 4 + rq;
        int row = m_base + rl;
        if (row < M) {
            short8 v = *(const short8*)&lds.ep[w][rl][l16 * 8];
            *(short8*)&H[(size_t)row * HID + n_base + l16 * 8] = v;
        }
    }
}

// ---------------- alpha body: logits per node/head + per-head global max ----------------

__device__ inline void alpha_body(int bid, int nb, const short* __restrict__ h,
                                  const float* __restrict__ a_src,
                                  const float* __restrict__ a_dst,
                                  float* __restrict__ alS, float* __restrict__ alD,
                                  unsigned* __restrict__ gmaxU, int n) {
    __shared__ unsigned sm[HEADS];
    int t = threadIdx.x;
    if (t < HEADS) sm[t] = 0u;
    __syncthreads();
    int head = t & 7;
    const float* as = a_src + head * CH;
    const float* ad = a_dst + head * CH;
    unsigned lmax = 0u;
    for (int idx = bid * 256 + t; idx < n * HEADS; idx += nb * 256) {
        int node = idx >> 3;
        const unsigned* hp = (const unsigned*)(h + (size_t)node * HID + head * CH);
        float s1 = 0.f, s2 = 0.f;
#pragma unroll
        for (int c = 0; c < 16; c++) {
            unsigned u = hp[c];
            float v0 = bflo(u), v1 = bfhi(u);
            s1 += v0 * as[2 * c] + v1 * as[2 * c + 1];
            s2 += v0 * ad[2 * c] + v1 * ad[2 * c + 1];
        }
        alS[idx] = s1;
        alD[idx] = s2;
        lmax = max(lmax, fkey(s1));
    }
    atomicMax(&sm[head], lmax);
    __syncthreads();
    if (t < HEADS) atomicMax(&gmaxU[t], sm[t]);
}

__device__ inline void scatter_body(int bid, const int* __restrict__ ei, int* cursor,
                                    int* srcs, int ne, int nn) {
    int i = bid * 256 + threadIdx.x;
    if (i < ne) {
        int s = ei[i];
        int d = ei[ne + i];
        int pos = atomicAdd(&cursor[d], 1);
        srcs[pos] = s;
    } else if (i < ne + nn) {
        int v = i - ne;
        int pos = atomicAdd(&cursor[v], 1);
        srcs[pos] = v;
    }
}

#define ALPHA_BLOCKS 512

__global__ __launch_bounds__(256) void alpha_kernel(const short* __restrict__ h,
                                                    const float* __restrict__ a_src,
                                                    const float* __restrict__ a_dst,
                                                    float* __restrict__ alS,
                                                    float* __restrict__ alD,
                                                    unsigned* __restrict__ gmaxU, int n) {
    alpha_body(blockIdx.x, gridDim.x, h, a_src, a_dst, alS, alD, gmaxU, n);
}

// fused: blocks [0,ALPHA_BLOCKS) do alpha for layer 0; the rest do CSR scatter
__global__ __launch_bounds__(256) void alpha_scatter_kernel(const short* __restrict__ h,
                                                            const float* __restrict__ a_src,
                                                            const float* __restrict__ a_dst,
                                                            float* __restrict__ alS,
                                                            float* __restrict__ alD,
                                                            unsigned* __restrict__ gmaxU, int n,
                                                            const int* __restrict__ ei,
                                                            int* cursor, int* srcs,
                                                            int ne, int nn) {
    if (blockIdx.x < ALPHA_BLOCKS)
        alpha_body(blockIdx.x, ALPHA_BLOCKS, h, a_src, a_dst, alS, alD, gmaxU, n);
    else
        scatter_body(blockIdx.x - ALPHA_BLOCKS, ei, cursor, srcs, ne, nn);
}

// ---------------- fused attention: fixed-shift softmax, lane-parallel weights ----------------
// one wave per node; lane = head*8+sub owns channels [lane*4, lane*4+4)

__global__ __launch_bounds__(256) void att_fused_kernel(const short* __restrict__ h,
                                                        const float* __restrict__ alS,
                                                        const float* __restrict__ alD,
                                                        const unsigned* __restrict__ gmaxU,
                                                        const int* __restrict__ row_ptr,
                                                        const int* __restrict__ srcs,
                                                        const float* __restrict__ bias,
                                                        short* __restrict__ out, int n) {
    int node = blockIdx.x * 4 + (threadIdx.x >> 6);
    if (node >= n) return;
    int lane = threadIdx.x & 63;
    int head = lane >> 3, sub = lane & 7;
    int lo = row_ptr[node], hi = row_ptr[node + 1];
    float ald = alD[node * HEADS + head];
    float gm = unfkey(gmaxU[head]) + ald;
    float m = fmaxf(gm, NEG_SLOPE * gm);
    int vbase = (lane & 56) << 2;
    int choff = lane * 4;

    float denom = 0.f;
    float4 acc = make_float4(0.f, 0.f, 0.f, 0.f);

    int i = lo;
    for (; i + 8 <= hi; i += 8) {
        int sj = srcs[i + sub];
        float x = alS[sj * HEADS + head] + ald;
        x = fmaxf(x, NEG_SLOPE * x);
        float wgt = __expf(x - m);
        denom += wgt;
        int wb = __builtin_bit_cast(int, wgt);
#pragma unroll
        for (int jj = 0; jj < 8; jj++) {
            float wj = __builtin_bit_cast(float,
                        __builtin_amdgcn_ds_bpermute(vbase + jj * 4, wb));
            int s = __builtin_amdgcn_readlane(sj, jj);
            uint2 u = *(const uint2*)&h[(size_t)s * HID + choff];
            acc.x += wj * bflo(u.x);
            acc.y += wj * bfhi(u.x);
            acc.z += wj * bflo(u.y);
            acc.w += wj * bfhi(u.y);
        }
    }
    if (i < hi) {
        int rem = hi - i;
        int sj = srcs[i + (sub < rem ? sub : 0)];
        float x = alS[sj * HEADS + head] + ald;
        x = fmaxf(x, NEG_SLOPE * x);
        float we = __expf(x - m);
        float wgt = (sub < rem) ? we : 0.f;
        denom += wgt;
        int wb = __builtin_bit_cast(int, wgt);
        for (int jj = 0; jj < rem; jj++) {
            float wj = __builtin_bit_cast(float,
                        __builtin_amdgcn_ds_bpermute(vbase + jj * 4, wb));
            int s = __builtin_amdgcn_readlane(sj, jj);
            uint2 u = *(const uint2*)&h[(size_t)s * HID + choff];
            acc.x += wj * bflo(u.x);
            acc.y += wj * bfhi(u.x);
            acc.z += wj * bflo(u.y);
            acc.w += wj * bfhi(u.y);
        }
    }
    denom += __shfl_xor(denom, 1);
    denom += __shfl_xor(denom, 2);
    denom += __shfl_xor(denom, 4);

    float inv = 1.0f / (denom + 1e-16f);
    float4 b4 = *(const float4*)&bias[choff];
    union { uint2 u; __hip_bfloat162 b[2]; } p;
    p.b[0] = __float22bfloat162_rn(make_float2(acc.x * inv + b4.x, acc.y * inv + b4.y));
    p.b[1] = __float22bfloat162_rn(make_float2(acc.z * inv + b4.z, acc.w * inv + b4.w));
    *(uint2*)&out[(size_t)node * HID + choff] = p.u;
}

// ---------------- parallel mean pool (bf16 input) ----------------

#define POOL_CHUNK 64

__global__ __launch_bounds__(256) void pool_accum_kernel(const short* __restrict__ h,
                                                         const int* __restrict__ batch,
                                                         float* __restrict__ pooled,
                                                         int* __restrict__ cnt, int n) {
    int c0 = blockIdx.x * POOL_CHUNK;
    int c1 = c0 + POOL_CHUNK; if (c1 > n) c1 = n;
    int t = threadIdx.x;
    int g_cur = batch[c0];
    float acc = 0.f;
    int run = 0;
    for (int i = c0; i < c1; i++) {
        int g = batch[i];
        if (g != g_cur) {
            atomicAdd(&pooled[g_cur * HID + t], acc);
            if (t == 0) atomicAdd(&cnt[g_cur], run);
            acc = 0.f; run = 0; g_cur = g;
        }
        acc += bf2f(h[(size_t)i * HID + t]);
        run++;
    }
    atomicAdd(&pooled[g_cur * HID + t], acc);
    if (t == 0) atomicAdd(&cnt[g_cur], run);
}

// ---------------- final linear (with mean divide) ----------------

__global__ void final_kernel(const float* __restrict__ pooled, const int* __restrict__ cnt,
                             const float* __restrict__ W, const float* __restrict__ b,
                             float* __restrict__ out) {
    int idx = blockIdx.x * blockDim.x + threadIdx.x;
    if (idx >= NGRAPH * 10) return;
    int g = idx / 10, o = idx % 10;
    int c = cnt[g];
    float inv = 1.0f / (float)(c > 0 ? c : 1);
    float acc = b[o];
    for (int k = 0; k < HID; k++) acc += pooled[g * HID + k] * inv * W[k * 10 + o];
    out[idx] = acc;
}

extern "C" void kernel_launch(void* const* d_in, const int* in_sizes, int n_in,
                              void* d_out, int out_size, void* d_ws, size_t ws_size,
                              hipStream_t stream) {
    const float* x      = (const float*)d_in[0];
    const int*   ei     = (const int*)d_in[1];
    const int*   batch  = (const int*)d_in[2];
    const float* W0     = (const float*)d_in[3];
    const float* a_src0 = (const float*)d_in[4];
    const float* a_dst0 = (const float*)d_in[5];
    const float* b0     = (const float*)d_in[6];
    const float* Wh     = (const float*)d_in[7];   // [2,256,256]
    const float* a_srch = (const float*)d_in[8];   // [2,8,32]
    const float* a_dsth = (const float*)d_in[9];
    const float* bh     = (const float*)d_in[10];  // [2,256]
    const float* W_lin  = (const float*)d_in[11];
    const float* b_lin  = (const float*)d_in[12];
    float* out = (float*)d_out;

    // workspace carve-up (pooled..counts contiguous for single memset)
    short* hA     = (short*)d_ws;                    // 50000*256 bf16 (GEMM out)
    short* hB     = hA + (size_t)NN * HID;           // 50000*256 bf16 (att out)
    short* Wt0    = hB + (size_t)NN * HID;           // 128*256 (swizzled)
    short* Wt1    = Wt0 + 256 * 128;                 // 256*256 (swizzled)
    short* Wt2    = Wt1 + 256 * 256;                 // 256*256 (swizzled)
    float* alS    = (float*)(Wt2 + 256 * 256);
    float* alD    = alS + (size_t)NN * HEADS;
    float* pooled = alD + (size_t)NN * HEADS;        // 128*256
    int* cnt      = (int*)(pooled + NGRAPH * HID);   // 128
    unsigned* gmaxA = (unsigned*)(cnt + NGRAPH);     // 24 (3 layers x 8 heads)
    int* counts   = (int*)(gmaxA + 24);              // 50000
    int* row_ptr  = counts + NN;                     // 50001
    int* cursor   = row_ptr + NN + 1;                // 50000
    int* srcs     = cursor + NN;                     // 850000
    int* partial  = srcs + (NE + NN);                // 64

    const int NEP = NE + NN;
    const int NB_SCAN = (NN + 1023) / 1024;          // 49 <= 64
    const int NB_CNT = (NE + 255) / 256;             // 3125
    const int NB_SCAT = (NEP + 255) / 256;           // 3321

    // single zero-init: pooled + cnt + gmaxA + counts
    hipMemsetAsync(pooled, 0, (NGRAPH * HID + NGRAPH + 24 + NN) * sizeof(float), stream);

    // fused W-swizzle + edge-count
    prep_kernel<<<768 + NB_CNT, 256, 0, stream>>>(W0, Wh, Wt0, Wt1, Wt2, ei + NE, counts, NE);
    scan_part_kernel<<<NB_SCAN, 1024, 0, stream>>>(counts, partial, NN);
    scan_final_kernel<<<NB_SCAN, 1024, 0, stream>>>(counts, partial, row_ptr, cursor, NN);

    const int gemm_grid = (NN + 127) / 128;          // 391 <= 512 resident: no tail
    const int agg_grid = (NN + 3) / 4;

    // layer 0: gemm, then fused alpha+scatter (scatter only gates att, not gemm)
    gemm_mfma_kernel<128, true><<<gemm_grid, 256, 0, stream>>>(x, Wt0, hA, NN);
    alpha_scatter_kernel<<<ALPHA_BLOCKS + NB_SCAT, 256, 0, stream>>>(
        hA, a_src0, a_dst0, alS, alD, gmaxA, NN, ei, cursor, srcs, NE, NN);
    att_fused_kernel<<<agg_grid, 256, 0, stream>>>(hA, alS, alD, gmaxA, row_ptr, srcs, b0, hB, NN);

    for (int l = 1; l < 3; l++) {
        const float* as = a_srch + (size_t)(l - 1) * HEADS * CH;
        const float* ad = a_dsth + (size_t)(l - 1) * HEADS * CH;
        const float* bb = bh + (size_t)(l - 1) * HID;
        unsigned* gm = gmaxA + l * 8;

        gemm_mfma_kernel<256, false><<<gemm_grid, 256, 0, stream>>>(
            hB, (l == 1) ? Wt1 : Wt2, hA, NN);
        alpha_kernel<<<ALPHA_BLOCKS, 256, 0, stream>>>(hA, as, ad, alS, alD, gm, NN);
        att_fused_kernel<<<agg_grid, 256, 0, stream>>>(hA, alS, alD, gm, row_ptr, srcs, bb, hB, NN);
    }

    // pool + final linear
    pool_accum_kernel<<<(NN + POOL_CHUNK - 1) / POOL_CHUNK, 256, 0, stream>>>(hB, batch, pooled, cnt, NN);
    final_kernel<<<(NGRAPH * 10 + 255) / 256, 256, 0, stream>>>(pooled, cnt, W_lin, b_lin, out);
}

// Round 14
// 515.374 us; speedup vs baseline: 1.0071x; 1.0071x over previous
//
#include <hip/hip_runtime.h>
#include <hip/hip_bf16.h>
#include <math.h>

#define NN 50000
#define NE 800000
#define NGRAPH 128
#define HEADS 8
#define CH 32
#define HID 256
#define NEG_SLOPE 0.2f

typedef __attribute__((ext_vector_type(8))) short short8;
typedef __attribute__((ext_vector_type(4))) short short4v;
typedef __attribute__((ext_vector_type(4))) float v4f;

__device__ inline float bflo(unsigned u) { return __builtin_bit_cast(float, u << 16); }
__device__ inline float bfhi(unsigned u) { return __builtin_bit_cast(float, u & 0xFFFF0000u); }
__device__ inline float bf2f(short s) {
    return __builtin_bit_cast(float, ((unsigned)(unsigned short)s) << 16);
}
__device__ inline short f2bf(float f) {
    __hip_bfloat16 b = __float2bfloat16(f);
    return __builtin_bit_cast(short, b);
}
// monotonic float<->uint order-preserving map (for atomicMax on floats)
__device__ inline unsigned fkey(float f) {
    unsigned u = __builtin_bit_cast(unsigned, f);
    return (u & 0x80000000u) ? ~u : (u | 0x80000000u);
}
__device__ inline float unfkey(unsigned u) {
    unsigned v = (u & 0x80000000u) ? (u & 0x7FFFFFFFu) : ~u;
    return __builtin_bit_cast(float, v);
}

// ---------------- fused prep: W swizzle-convert (blocks 0..767) + edge count (rest) ----------------
// counts[] pre-zeroed by memset; self-loop handled as +1 inside the scans.

__global__ void prep_kernel(const float* __restrict__ W0, const float* __restrict__ Wh,
                            short* __restrict__ Wt0, short* __restrict__ Wt1,
                            short* __restrict__ Wt2,
                            const int* __restrict__ dst, int* __restrict__ counts, int e) {
    int b = blockIdx.x;
    if (b < 768) {
        int which = b >> 8;
        int n = b & 255;
        const float* W = (which == 0) ? W0 : (which == 1) ? Wh : Wh + 256 * 256;
        short* Wt = (which == 0) ? Wt0 : (which == 1) ? Wt1 : Wt2;
        int K = (which == 0) ? 128 : 256;
        int tile16 = n >> 4, l16 = n & 15;
        int KC = K >> 5;
        for (int k = threadIdx.x; k < K; k += blockDim.x) {
            int kc = k >> 5, quad = (k & 31) >> 3, j = k & 7;
            int lane = quad * 16 + l16;
            Wt[(size_t)(((tile16 * KC + kc) * 64 + lane)) * 8 + j] = f2bf(W[(size_t)k * 256 + n]);
        }
    } else {
        int i = (b - 768) * 256 + threadIdx.x;
        if (i < e) atomicAdd(&counts[dst[i]], 1);
    }
}

__device__ inline int wave_incl_scan(int v, int lane) {
#pragma unroll
    for (int off = 1; off < 64; off <<= 1) {
        int u = __shfl_up(v, off);
        if (lane >= off) v += u;
    }
    return v;
}

__global__ __launch_bounds__(1024) void scan_part_kernel(const int* __restrict__ counts,
                                                         int* partial, int n) {
    int i = blockIdx.x * 1024 + threadIdx.x;
    int v = (i < n) ? counts[i] + 1 : 0;   // +1 self-loop
    int lane = threadIdx.x & 63, w = threadIdx.x >> 6;
    __shared__ int ws[16];
    int sv = wave_incl_scan(v, lane);
    if (lane == 63) ws[w] = sv;
    __syncthreads();
    if (threadIdx.x == 0) {
        int tot = 0;
#pragma unroll
        for (int j = 0; j < 16; j++) tot += ws[j];
        partial[blockIdx.x] = tot;
    }
}

// final scan; block-offset computed inline from partials (nb <= 64)
__global__ __launch_bounds__(1024) void scan_final_kernel(const int* __restrict__ counts,
                                                          const int* __restrict__ partial,
                                                          int* row_ptr, int* cursor, int n) {
    __shared__ int ws[17];
    __shared__ int s_off;
    int i = blockIdx.x * 1024 + threadIdx.x;
    int v = (i < n) ? counts[i] + 1 : 0;   // +1 self-loop
    int lane = threadIdx.x & 63, w = threadIdx.x >> 6;
    if (threadIdx.x < 64) {
        int pv = ((int)threadIdx.x < (int)blockIdx.x) ? partial[threadIdx.x] : 0;
#pragma unroll
        for (int off = 1; off < 64; off <<= 1) pv += __shfl_xor(pv, off);
        if (threadIdx.x == 0) s_off = pv;
    }
    int sv = wave_incl_scan(v, lane);
    if (lane == 63) ws[w] = sv;
    __syncthreads();
    if (w == 0) {
        int t = (lane < 16) ? ws[lane] : 0;
        int ts = wave_incl_scan(t, lane);
        if (lane < 16) ws[lane] = ts;
    }
    __syncthreads();
    int waveBase = (w > 0) ? ws[w - 1] : 0;
    int off = s_off;
    int incl = waveBase + sv;
    if (i < n) {
        int ex = off + incl - v;
        row_ptr[i] = ex;
        cursor[i] = ex;
        if (i == n - 1) row_ptr[n] = off + incl;
    }
}

__global__ void scatter_kernel(const int* __restrict__ ei, int* cursor, int* srcs, int ne, int nn) {
    int i = blockIdx.x * blockDim.x + threadIdx.x;
    if (i < ne) {
        int s = ei[i];
        int d = ei[ne + i];
        int pos = atomicAdd(&cursor[d], 1);
        srcs[pos] = s;
    } else if (i < ne + nn) {
        int v = i - ne;
        int pos = atomicAdd(&cursor[v], 1);
        srcs[pos] = v;
    }
}

// ---------------- MFMA GEMM: H[M,256](bf16) = A[M,K] @ W (swizzled bf16) ----------------
// block = 128 rows x 256 cols, 4 waves; wave = 64 rows x 128 cols (4x8 mfma tiles).
// 32 MFMA per 8 B-loads (4:1); grid 391 <= 512 resident (no tail rounds).
// A staged coalesced in LDS (union with epilogue tile); B coalesced via swizzle.

#define EP_STRIDE 144

template <int K, bool AF32>
__global__ __launch_bounds__(256, 2) void gemm_mfma_kernel(const void* __restrict__ Ap,
                                                           const short* __restrict__ Wt,
                                                           short* __restrict__ H,
                                                           int M) {
    constexpr int KC = K >> 5;
    constexpr int ASTRIDE = K + 8;
    union LdsU {
        short a[128][ASTRIDE];
        short ep[4][64][EP_STRIDE];
    };
    __shared__ LdsU lds;

    int t = threadIdx.x;
    int w = t >> 6;
    int lane = t & 63;
    int quad = lane >> 4, l16 = lane & 15;
    int wm = w & 1, wn = w >> 1;
    int m0 = blockIdx.x * 128;
    int m_base = m0 + wm * 64;
    int n_base = wn * 128;

    // ---- stage A[128][K] into LDS, fully coalesced global reads ----
    if constexpr (AF32) {
        constexpr int C4 = K / 4;
        const float* A = (const float*)Ap;
        for (int s = t; s < 128 * C4; s += 256) {
            int row = s / C4;
            int c4 = s % C4;
            int gr = m0 + row; if (gr >= M) gr = M - 1;
            float4 v = *(const float4*)&A[(size_t)gr * K + c4 * 4];
            union { short4v s4; __hip_bfloat162 b[2]; } p;
            p.b[0] = __float22bfloat162_rn(make_float2(v.x, v.y));
            p.b[1] = __float22bfloat162_rn(make_float2(v.z, v.w));
            *(short4v*)&lds.a[row][c4 * 4] = p.s4;
        }
    } else {
        constexpr int C8 = K / 8;
        const short* A = (const short*)Ap;
        for (int s = t; s < 128 * C8; s += 256) {
            int row = s / C8;
            int c8 = s % C8;
            int gr = m0 + row; if (gr >= M) gr = M - 1;
            *(short8*)&lds.a[row][c8 * 8] = *(const short8*)&A[(size_t)gr * K + c8 * 8];
        }
    }
    __syncthreads();

    v4f acc[4][8] = {};
    // swizzled B base for this wave: tiles wn*8 .. wn*8+7
    const short* bw = Wt + ((size_t)(wn * 8) * KC * 64 + lane) * 8;

#pragma unroll
    for (int kc = 0; kc < KC; kc++) {
        short8 b_frag[8];
#pragma unroll
        for (int nj = 0; nj < 8; nj++)
            b_frag[nj] = *(const short8*)(bw + (size_t)(nj * KC + kc) * 64 * 8);
        short8 a_frag[4];
#pragma unroll
        for (int mi = 0; mi < 4; mi++)
            a_frag[mi] = *(const short8*)&lds.a[wm * 64 + mi * 16 + l16][kc * 32 + quad * 8];
#pragma unroll
        for (int mi = 0; mi < 4; mi++)
#pragma unroll
            for (int nj = 0; nj < 8; nj++)
                acc[mi][nj] = __builtin_amdgcn_mfma_f32_16x16x32_bf16(a_frag[mi], b_frag[nj],
                                                                      acc[mi][nj], 0, 0, 0);
    }
    __syncthreads();   // all lds.a reads complete before ep overwrite

#pragma unroll
    for (int mi = 0; mi < 4; mi++)
#pragma unroll
        for (int r = 0; r < 4; r++) {
            int rl = mi * 16 + quad * 4 + r;
#pragma unroll
            for (int nj = 0; nj < 8; nj++)
                lds.ep[w][rl][nj * 16 + l16] = f2bf(acc[mi][nj][r]);
        }
    __syncthreads();

    int rq = lane >> 4;
#pragma unroll
    for (int it = 0; it < 16; it++) {
        int rl = it * 4 + rq;
        int row = m_base + rl;
        if (row < M) {
            short8 v = *(const short8*)&lds.ep[w][rl][l16 * 8];
            *(short8*)&H[(size_t)row * HID + n_base + l16 * 8] = v;
        }
    }
}

// ---------------- attention logits per node/head + fused per-head global max ----------------

__global__ __launch_bounds__(256) void alpha_kernel(const short* __restrict__ h,
                                                    const float* __restrict__ a_src,
                                                    const float* __restrict__ a_dst,
                                                    float* __restrict__ alS,
                                                    float* __restrict__ alD,
                                                    unsigned* __restrict__ gmaxU, int n) {
    __shared__ unsigned sm[HEADS];
    int t = threadIdx.x;
    if (t < HEADS) sm[t] = 0u;
    __syncthreads();
    int head = t & 7;
    const float* as = a_src + head * CH;
    const float* ad = a_dst + head * CH;
    unsigned lmax = 0u;
    for (int idx = blockIdx.x * 256 + t; idx < n * HEADS; idx += gridDim.x * 256) {
        int node = idx >> 3;
        const unsigned* hp = (const unsigned*)(h + (size_t)node * HID + head * CH);
        float s1 = 0.f, s2 = 0.f;
#pragma unroll
        for (int c = 0; c < 16; c++) {
            unsigned u = hp[c];
            float v0 = bflo(u), v1 = bfhi(u);
            s1 += v0 * as[2 * c] + v1 * as[2 * c + 1];
            s2 += v0 * ad[2 * c] + v1 * ad[2 * c + 1];
        }
        alS[idx] = s1;
        alD[idx] = s2;
        lmax = max(lmax, fkey(s1));
    }
    atomicMax(&sm[head], lmax);
    __syncthreads();
    if (t < HEADS) atomicMax(&gmaxU[t], sm[t]);
}

// ---------------- fused attention: fixed-shift softmax, lane-parallel weights ----------------
// one wave per node; lane = head*8+sub owns channels [lane*4, lane*4+4)

__global__ __launch_bounds__(256) void att_fused_kernel(const short* __restrict__ h,
                                                        const float* __restrict__ alS,
                                                        const float* __restrict__ alD,
                                                        const unsigned* __restrict__ gmaxU,
                                                        const int* __restrict__ row_ptr,
                                                        const int* __restrict__ srcs,
                                                        const float* __restrict__ bias,
                                                        short* __restrict__ out, int n) {
    int node = blockIdx.x * 4 + (threadIdx.x >> 6);
    if (node >= n) return;
    int lane = threadIdx.x & 63;
    int head = lane >> 3, sub = lane & 7;
    int lo = row_ptr[node], hi = row_ptr[node + 1];
    float ald = alD[node * HEADS + head];
    float gm = unfkey(gmaxU[head]) + ald;
    float m = fmaxf(gm, NEG_SLOPE * gm);
    int vbase = (lane & 56) << 2;
    int choff = lane * 4;

    float denom = 0.f;
    float4 acc = make_float4(0.f, 0.f, 0.f, 0.f);

    int i = lo;
    for (; i + 8 <= hi; i += 8) {
        int sj = srcs[i + sub];
        float x = alS[sj * HEADS + head] + ald;
        x = fmaxf(x, NEG_SLOPE * x);
        float wgt = __expf(x - m);
        denom += wgt;
        int wb = __builtin_bit_cast(int, wgt);
#pragma unroll
        for (int jj = 0; jj < 8; jj++) {
            float wj = __builtin_bit_cast(float,
                        __builtin_amdgcn_ds_bpermute(vbase + jj * 4, wb));
            int s = __builtin_amdgcn_readlane(sj, jj);
            uint2 u = *(const uint2*)&h[(size_t)s * HID + choff];
            acc.x += wj * bflo(u.x);
            acc.y += wj * bfhi(u.x);
            acc.z += wj * bflo(u.y);
            acc.w += wj * bfhi(u.y);
        }
    }
    if (i < hi) {
        int rem = hi - i;
        int sj = srcs[i + (sub < rem ? sub : 0)];
        float x = alS[sj * HEADS + head] + ald;
        x = fmaxf(x, NEG_SLOPE * x);
        float we = __expf(x - m);
        float wgt = (sub < rem) ? we : 0.f;
        denom += wgt;
        int wb = __builtin_bit_cast(int, wgt);
        for (int jj = 0; jj < rem; jj++) {
            float wj = __builtin_bit_cast(float,
                        __builtin_amdgcn_ds_bpermute(vbase + jj * 4, wb));
            int s = __builtin_amdgcn_readlane(sj, jj);
            uint2 u = *(const uint2*)&h[(size_t)s * HID + choff];
            acc.x += wj * bflo(u.x);
            acc.y += wj * bfhi(u.x);
            acc.z += wj * bflo(u.y);
            acc.w += wj * bfhi(u.y);
        }
    }
    denom += __shfl_xor(denom, 1);
    denom += __shfl_xor(denom, 2);
    denom += __shfl_xor(denom, 4);

    float inv = 1.0f / (denom + 1e-16f);
    float4 b4 = *(const float4*)&bias[choff];
    union { uint2 u; __hip_bfloat162 b[2]; } p;
    p.b[0] = __float22bfloat162_rn(make_float2(acc.x * inv + b4.x, acc.y * inv + b4.y));
    p.b[1] = __float22bfloat162_rn(make_float2(acc.z * inv + b4.z, acc.w * inv + b4.w));
    *(uint2*)&out[(size_t)node * HID + choff] = p.u;
}

// ---------------- parallel mean pool (bf16 input) ----------------

#define POOL_CHUNK 64

__global__ __launch_bounds__(256) void pool_accum_kernel(const short* __restrict__ h,
                                                         const int* __restrict__ batch,
                                                         float* __restrict__ pooled,
                                                         int* __restrict__ cnt, int n) {
    int c0 = blockIdx.x * POOL_CHUNK;
    int c1 = c0 + POOL_CHUNK; if (c1 > n) c1 = n;
    int t = threadIdx.x;
    int g_cur = batch[c0];
    float acc = 0.f;
    int run = 0;
    for (int i = c0; i < c1; i++) {
        int g = batch[i];
        if (g != g_cur) {
            atomicAdd(&pooled[g_cur * HID + t], acc);
            if (t == 0) atomicAdd(&cnt[g_cur], run);
            acc = 0.f; run = 0; g_cur = g;
        }
        acc += bf2f(h[(size_t)i * HID + t]);
        run++;
    }
    atomicAdd(&pooled[g_cur * HID + t], acc);
    if (t == 0) atomicAdd(&cnt[g_cur], run);
}

// ---------------- final linear (with mean divide) ----------------

__global__ void final_kernel(const float* __restrict__ pooled, const int* __restrict__ cnt,
                             const float* __restrict__ W, const float* __restrict__ b,
                             float* __restrict__ out) {
    int idx = blockIdx.x * blockDim.x + threadIdx.x;
    if (idx >= NGRAPH * 10) return;
    int g = idx / 10, o = idx % 10;
    int c = cnt[g];
    float inv = 1.0f / (float)(c > 0 ? c : 1);
    float acc = b[o];
    for (int k = 0; k < HID; k++) acc += pooled[g * HID + k] * inv * W[k * 10 + o];
    out[idx] = acc;
}

extern "C" void kernel_launch(void* const* d_in, const int* in_sizes, int n_in,
                              void* d_out, int out_size, void* d_ws, size_t ws_size,
                              hipStream_t stream) {
    const float* x      = (const float*)d_in[0];
    const int*   ei     = (const int*)d_in[1];
    const int*   batch  = (const int*)d_in[2];
    const float* W0     = (const float*)d_in[3];
    const float* a_src0 = (const float*)d_in[4];
    const float* a_dst0 = (const float*)d_in[5];
    const float* b0     = (const float*)d_in[6];
    const float* Wh     = (const float*)d_in[7];   // [2,256,256]
    const float* a_srch = (const float*)d_in[8];   // [2,8,32]
    const float* a_dsth = (const float*)d_in[9];
    const float* bh     = (const float*)d_in[10];  // [2,256]
    const float* W_lin  = (const float*)d_in[11];
    const float* b_lin  = (const float*)d_in[12];
    float* out = (float*)d_out;

    // workspace carve-up (pooled..counts contiguous for single memset)
    short* hA     = (short*)d_ws;                    // 50000*256 bf16 (GEMM out)
    short* hB     = hA + (size_t)NN * HID;           // 50000*256 bf16 (att out)
    short* Wt0    = hB + (size_t)NN * HID;           // 128*256 (swizzled)
    short* Wt1    = Wt0 + 256 * 128;                 // 256*256 (swizzled)
    short* Wt2    = Wt1 + 256 * 256;                 // 256*256 (swizzled)
    float* alS    = (float*)(Wt2 + 256 * 256);
    float* alD    = alS + (size_t)NN * HEADS;
    float* pooled = alD + (size_t)NN * HEADS;        // 128*256
    int* cnt      = (int*)(pooled + NGRAPH * HID);   // 128
    unsigned* gmaxA = (unsigned*)(cnt + NGRAPH);     // 24 (3 layers x 8 heads)
    int* counts   = (int*)(gmaxA + 24);              // 50000
    int* row_ptr  = counts + NN;                     // 50001
    int* cursor   = row_ptr + NN + 1;                // 50000
    int* srcs     = cursor + NN;                     // 850000
    int* partial  = srcs + (NE + NN);                // 64

    const int NEP = NE + NN;
    const int NB_SCAN = (NN + 1023) / 1024;          // 49 <= 64
    const int NB_CNT = (NE + 255) / 256;             // 3125

    // single zero-init: pooled + cnt + gmaxA + counts
    hipMemsetAsync(pooled, 0, (NGRAPH * HID + NGRAPH + 24 + NN) * sizeof(float), stream);

    // fused W-swizzle + edge-count
    prep_kernel<<<768 + NB_CNT, 256, 0, stream>>>(W0, Wh, Wt0, Wt1, Wt2, ei + NE, counts, NE);
    scan_part_kernel<<<NB_SCAN, 1024, 0, stream>>>(counts, partial, NN);
    scan_final_kernel<<<NB_SCAN, 1024, 0, stream>>>(counts, partial, row_ptr, cursor, NN);
    scatter_kernel<<<(NEP + 255) / 256, 256, 0, stream>>>(ei, cursor, srcs, NE, NN);

    const int gemm_grid = (NN + 127) / 128;          // 391 <= 512 resident: no tail
    const int agg_grid = (NN + 3) / 4;

    for (int l = 0; l < 3; l++) {
        const float* as = (l == 0) ? a_src0 : a_srch + (size_t)(l - 1) * HEADS * CH;
        const float* ad = (l == 0) ? a_dst0 : a_dsth + (size_t)(l - 1) * HEADS * CH;
        const float* bb = (l == 0) ? b0 : bh + (size_t)(l - 1) * HID;
        unsigned* gm = gmaxA + l * 8;

        if (l == 0)
            gemm_mfma_kernel<128, true><<<gemm_grid, 256, 0, stream>>>(x, Wt0, hA, NN);
        else
            gemm_mfma_kernel<256, false><<<gemm_grid, 256, 0, stream>>>(
                hB, (l == 1) ? Wt1 : Wt2, hA, NN);
        alpha_kernel<<<512, 256, 0, stream>>>(hA, as, ad, alS, alD, gm, NN);
        att_fused_kernel<<<agg_grid, 256, 0, stream>>>(hA, alS, alD, gm, row_ptr, srcs, bb, hB, NN);
    }

    // pool + final linear
    pool_accum_kernel<<<(NN + POOL_CHUNK - 1) / POOL_CHUNK, 256, 0, stream>>>(hB, batch, pooled, cnt, NN);
    final_kernel<<<(NGRAPH * 10 + 255) / 256, 256, 0, stream>>>(pooled, cnt, W_lin, b_lin, out);
}

// Round 16
// 490.184 us; speedup vs baseline: 1.0588x; 1.0514x over previous
//
#include <hip/hip_runtime.h>
#include <hip/hip_bf16.h>
#include <math.h>

#define NN 50000
#define NE 800000
#define NGRAPH 128
#define HEADS 8
#define CH 32
#define HID 256
#define NEG_SLOPE 0.2f

typedef __attribute__((ext_vector_type(8))) short short8;
typedef __attribute__((ext_vector_type(4))) short short4v;
typedef __attribute__((ext_vector_type(4))) float v4f;

__device__ inline float bflo(unsigned u) { return __builtin_bit_cast(float, u << 16); }
__device__ inline float bfhi(unsigned u) { return __builtin_bit_cast(float, u & 0xFFFF0000u); }
__device__ inline float bf2f(short s) {
    return __builtin_bit_cast(float, ((unsigned)(unsigned short)s) << 16);
}
__device__ inline short f2bf(float f) {
    __hip_bfloat16 b = __float2bfloat16(f);
    return __builtin_bit_cast(short, b);
}
// monotonic float<->uint order-preserving map (for atomicMax on floats)
__device__ inline unsigned fkey(float f) {
    unsigned u = __builtin_bit_cast(unsigned, f);
    return (u & 0x80000000u) ? ~u : (u | 0x80000000u);
}
__device__ inline float unfkey(unsigned u) {
    unsigned v = (u & 0x80000000u) ? (u & 0x7FFFFFFFu) : ~u;
    return __builtin_bit_cast(float, v);
}

// ---------------- fused prep ----------------
// blocks [0, 816): W swizzle-convert; per layer 272 cols: 0..255 = W cols,
//   cols 256..271 = wa[k][j] = sum_c W[k][head*32+c] * a[c]  (j<8: a_src head j; j>=8: a_dst head j-8)
// remaining blocks: edge count. counts[] pre-zeroed; self-loop = +1 in scans.

__global__ void prep_kernel(const float* __restrict__ W0, const float* __restrict__ Wh,
                            const float* __restrict__ as0, const float* __restrict__ ad0,
                            const float* __restrict__ ash, const float* __restrict__ adh,
                            short* __restrict__ Wt0, short* __restrict__ Wt1,
                            short* __restrict__ Wt2,
                            const int* __restrict__ dst, int* __restrict__ counts, int e) {
    int b = blockIdx.x;
    if (b < 816) {
        int which = b / 272;
        int n = b % 272;
        const float* W = (which == 0) ? W0 : (which == 1) ? Wh : Wh + 256 * 256;
        short* Wt = (which == 0) ? Wt0 : (which == 1) ? Wt1 : Wt2;
        const float* as = (which == 0) ? as0 : ash + (which - 1) * HEADS * CH;
        const float* ad = (which == 0) ? ad0 : adh + (which - 1) * HEADS * CH;
        int K = (which == 0) ? 128 : 256;
        int tile16 = n >> 4, l16 = n & 15;
        int KC = K >> 5;
        for (int k = threadIdx.x; k < K; k += blockDim.x) {
            float val;
            if (n < 256) {
                val = W[(size_t)k * 256 + n];
            } else {
                int j = n - 256;
                int head = j & 7;
                const float* a = (j < 8) ? (as + head * CH) : (ad + head * CH);
                float s = 0.f;
#pragma unroll
                for (int c = 0; c < CH; c++) s += W[(size_t)k * 256 + head * CH + c] * a[c];
                val = s;
            }
            int kc = k >> 5, quad = (k & 31) >> 3, j8 = k & 7;
            int lane = quad * 16 + l16;
            Wt[(size_t)(((tile16 * KC + kc) * 64 + lane)) * 8 + j8] = f2bf(val);
        }
    } else {
        int i = (b - 816) * 256 + threadIdx.x;
        if (i < e) atomicAdd(&counts[dst[i]], 1);
    }
}

__device__ inline int wave_incl_scan(int v, int lane) {
#pragma unroll
    for (int off = 1; off < 64; off <<= 1) {
        int u = __shfl_up(v, off);
        if (lane >= off) v += u;
    }
    return v;
}

__global__ __launch_bounds__(1024) void scan_part_kernel(const int* __restrict__ counts,
                                                         int* partial, int n) {
    int i = blockIdx.x * 1024 + threadIdx.x;
    int v = (i < n) ? counts[i] + 1 : 0;   // +1 self-loop
    int lane = threadIdx.x & 63, w = threadIdx.x >> 6;
    __shared__ int ws[16];
    int sv = wave_incl_scan(v, lane);
    if (lane == 63) ws[w] = sv;
    __syncthreads();
    if (threadIdx.x == 0) {
        int tot = 0;
#pragma unroll
        for (int j = 0; j < 16; j++) tot += ws[j];
        partial[blockIdx.x] = tot;
    }
}

// final scan; block-offset computed inline from partials (nb <= 64)
__global__ __launch_bounds__(1024) void scan_final_kernel(const int* __restrict__ counts,
                                                          const int* __restrict__ partial,
                                                          int* row_ptr, int* cursor, int n) {
    __shared__ int ws[17];
    __shared__ int s_off;
    int i = blockIdx.x * 1024 + threadIdx.x;
    int v = (i < n) ? counts[i] + 1 : 0;   // +1 self-loop
    int lane = threadIdx.x & 63, w = threadIdx.x >> 6;
    if (threadIdx.x < 64) {
        int pv = ((int)threadIdx.x < (int)blockIdx.x) ? partial[threadIdx.x] : 0;
#pragma unroll
        for (int off = 1; off < 64; off <<= 1) pv += __shfl_xor(pv, off);
        if (threadIdx.x == 0) s_off = pv;
    }
    int sv = wave_incl_scan(v, lane);
    if (lane == 63) ws[w] = sv;
    __syncthreads();
    if (w == 0) {
        int t = (lane < 16) ? ws[lane] : 0;
        int ts = wave_incl_scan(t, lane);
        if (lane < 16) ws[lane] = ts;
    }
    __syncthreads();
    int waveBase = (w > 0) ? ws[w - 1] : 0;
    int off = s_off;
    int incl = waveBase + sv;
    if (i < n) {
        int ex = off + incl - v;
        row_ptr[i] = ex;
        cursor[i] = ex;
        if (i == n - 1) row_ptr[n] = off + incl;
    }
}

__global__ void scatter_kernel(const int* __restrict__ ei, int* cursor, int* srcs, int ne, int nn) {
    int i = blockIdx.x * blockDim.x + threadIdx.x;
    if (i < ne) {
        int s = ei[i];
        int d = ei[ne + i];
        int pos = atomicAdd(&cursor[d], 1);
        srcs[pos] = s;
    } else if (i < ne + nn) {
        int v = i - ne;
        int pos = atomicAdd(&cursor[v], 1);
        srcs[pos] = v;
    }
}

// ---------------- MFMA GEMM + algebraic alpha (17th B-tile) ----------------
// H[M,256](bf16) = A[M,K] @ W(swizzled, 17 tiles); tile 16 = wa -> alS/alD in f32 acc.
// block = 128 rows x 256 cols, 4 waves; wave = 64 rows x 128 cols (4x8 mfma tiles).
// Waves with wn==0 additionally compute the wa tile for their 64 rows (+4 MFMA/kc).

#define EP_STRIDE 144

template <int K, bool AF32>
__global__ __launch_bounds__(256, 2) void gemm_mfma_kernel(const void* __restrict__ Ap,
                                                           const short* __restrict__ Wt,
                                                           short* __restrict__ H,
                                                           float* __restrict__ alS,
                                                           float* __restrict__ alD,
                                                           unsigned* __restrict__ gmaxU,
                                                           int M) {
    constexpr int KC = K >> 5;
    constexpr int ASTRIDE = K + 8;
    union LdsU {
        short a[128][ASTRIDE];
        short ep[4][64][EP_STRIDE];
    };
    __shared__ LdsU lds;
    __shared__ unsigned sm[HEADS];

    int t = threadIdx.x;
    int w = t >> 6;
    int lane = t & 63;
    int quad = lane >> 4, l16 = lane & 15;
    int wm = w & 1, wn = w >> 1;
    int m0 = blockIdx.x * 128;
    int m_base = m0 + wm * 64;
    int n_base = wn * 128;

    if (t < HEADS) sm[t] = 0u;

    // ---- stage A[128][K] into LDS, fully coalesced global reads ----
    if constexpr (AF32) {
        constexpr int C4 = K / 4;
        const float* A = (const float*)Ap;
        for (int s = t; s < 128 * C4; s += 256) {
            int row = s / C4;
            int c4 = s % C4;
            int gr = m0 + row; if (gr >= M) gr = M - 1;
            float4 v = *(const float4*)&A[(size_t)gr * K + c4 * 4];
            union { short4v s4; __hip_bfloat162 b[2]; } p;
            p.b[0] = __float22bfloat162_rn(make_float2(v.x, v.y));
            p.b[1] = __float22bfloat162_rn(make_float2(v.z, v.w));
            *(short4v*)&lds.a[row][c4 * 4] = p.s4;
        }
    } else {
        constexpr int C8 = K / 8;
        const short* A = (const short*)Ap;
        for (int s = t; s < 128 * C8; s += 256) {
            int row = s / C8;
            int c8 = s % C8;
            int gr = m0 + row; if (gr >= M) gr = M - 1;
            *(short8*)&lds.a[row][c8 * 8] = *(const short8*)&A[(size_t)gr * K + c8 * 8];
        }
    }
    __syncthreads();

    v4f acc[4][8] = {};
    v4f acce[4] = {};   // wa tile accumulators (wn==0 waves only; cols: l16<8 -> alS, else alD)
    // swizzled B base for this wave: tiles wn*8 .. wn*8+7
    const short* bw = Wt + ((size_t)(wn * 8) * KC * 64 + lane) * 8;
    const short* bwe = Wt + ((size_t)(16) * KC * 64 + lane) * 8;   // wa tile

#pragma unroll
    for (int kc = 0; kc < KC; kc++) {
        short8 b_frag[8];
#pragma unroll
        for (int nj = 0; nj < 8; nj++)
            b_frag[nj] = *(const short8*)(bw + (size_t)(nj * KC + kc) * 64 * 8);
        short8 a_frag[4];
#pragma unroll
        for (int mi = 0; mi < 4; mi++)
            a_frag[mi] = *(const short8*)&lds.a[wm * 64 + mi * 16 + l16][kc * 32 + quad * 8];
#pragma unroll
        for (int mi = 0; mi < 4; mi++)
#pragma unroll
            for (int nj = 0; nj < 8; nj++)
                acc[mi][nj] = __builtin_amdgcn_mfma_f32_16x16x32_bf16(a_frag[mi], b_frag[nj],
                                                                      acc[mi][nj], 0, 0, 0);
        if (wn == 0) {
            short8 be = *(const short8*)(bwe + (size_t)kc * 64 * 8);
#pragma unroll
            for (int mi = 0; mi < 4; mi++)
                acce[mi] = __builtin_amdgcn_mfma_f32_16x16x32_bf16(a_frag[mi], be,
                                                                   acce[mi], 0, 0, 0);
        }
    }
    __syncthreads();   // all lds.a reads complete before ep overwrite

    // ---- alS/alD write + per-head max (wn==0 waves; rows m_base..m_base+63) ----
    if (wn == 0) {
        float hmax = -1e30f;   // head = l16 (only meaningful for l16 < 8)
#pragma unroll
        for (int mi = 0; mi < 4; mi++)
#pragma unroll
            for (int r = 0; r < 4; r++) {
                int row = m_base + mi * 16 + quad * 4 + r;
                float v = acce[mi][r];
                if (row < M) {
                    if (l16 < 8) {
                        alS[row * HEADS + l16] = v;
                        hmax = fmaxf(hmax, v);
                    } else {
                        alD[row * HEADS + (l16 - 8)] = v;
                    }
                }
            }
        hmax = fmaxf(hmax, __shfl_xor(hmax, 16));
        hmax = fmaxf(hmax, __shfl_xor(hmax, 32));
        if (lane < 8) atomicMax(&sm[lane], fkey(hmax));
    }

#pragma unroll
    for (int mi = 0; mi < 4; mi++)
#pragma unroll
        for (int r = 0; r < 4; r++) {
            int rl = mi * 16 + quad * 4 + r;
#pragma unroll
            for (int nj = 0; nj < 8; nj++)
                lds.ep[w][rl][nj * 16 + l16] = f2bf(acc[mi][nj][r]);
        }
    __syncthreads();

    int rq = lane >> 4;
#pragma unroll
    for (int it = 0; it < 16; it++) {
        int rl = it * 4 + rq;
        int row = m_base + rl;
        if (row < M) {
            short8 v = *(const short8*)&lds.ep[w][rl][l16 * 8];
            *(short8*)&H[(size_t)row * HID + n_base + l16 * 8] = v;
        }
    }
    if (t < HEADS) atomicMax(&gmaxU[t], sm[t]);
}

// ---------------- fused attention: fixed-shift softmax, lane-parallel weights ----------------
// one wave per node; lane = head*8+sub owns channels [lane*4, lane*4+4)

__global__ __launch_bounds__(256) void att_fused_kernel(const short* __restrict__ h,
                                                        const float* __restrict__ alS,
                                                        const float* __restrict__ alD,
                                                        const unsigned* __restrict__ gmaxU,
                                                        const int* __restrict__ row_ptr,
                                                        const int* __restrict__ srcs,
                                                        const float* __restrict__ bias,
                                                        short* __restrict__ out, int n) {
    int node = blockIdx.x * 4 + (threadIdx.x >> 6);
    if (node >= n) return;
    int lane = threadIdx.x & 63;
    int head = lane >> 3, sub = lane & 7;
    int lo = row_ptr[node], hi = row_ptr[node + 1];
    float ald = alD[node * HEADS + head];
    float gm = unfkey(gmaxU[head]) + ald;
    float m = fmaxf(gm, NEG_SLOPE * gm);
    int vbase = (lane & 56) << 2;
    int choff = lane * 4;

    float denom = 0.f;
    float4 acc = make_float4(0.f, 0.f, 0.f, 0.f);

    int i = lo;
    for (; i + 8 <= hi; i += 8) {
        int sj = srcs[i + sub];
        float x = alS[sj * HEADS + head] + ald;
        x = fmaxf(x, NEG_SLOPE * x);
        float wgt = __expf(x - m);
        denom += wgt;
        int wb = __builtin_bit_cast(int, wgt);
#pragma unroll
        for (int jj = 0; jj < 8; jj++) {
            float wj = __builtin_bit_cast(float,
                        __builtin_amdgcn_ds_bpermute(vbase + jj * 4, wb));
            int s = __builtin_amdgcn_readlane(sj, jj);
            uint2 u = *(const uint2*)&h[(size_t)s * HID + choff];
            acc.x += wj * bflo(u.x);
            acc.y += wj * bfhi(u.x);
            acc.z += wj * bflo(u.y);
            acc.w += wj * bfhi(u.y);
        }
    }
    if (i < hi) {
        int rem = hi - i;
        int sj = srcs[i + (sub < rem ? sub : 0)];
        float x = alS[sj * HEADS + head] + ald;
        x = fmaxf(x, NEG_SLOPE * x);
        float we = __expf(x - m);
        float wgt = (sub < rem) ? we : 0.f;
        denom += wgt;
        int wb = __builtin_bit_cast(int, wgt);
        for (int jj = 0; jj < rem; jj++) {
            float wj = __builtin_bit_cast(float,
                        __builtin_amdgcn_ds_bpermute(vbase + jj * 4, wb));
            int s = __builtin_amdgcn_readlane(sj, jj);
            uint2 u = *(const uint2*)&h[(size_t)s * HID + choff];
            acc.x += wj * bflo(u.x);
            acc.y += wj * bfhi(u.x);
            acc.z += wj * bflo(u.y);
            acc.w += wj * bfhi(u.y);
        }
    }
    denom += __shfl_xor(denom, 1);
    denom += __shfl_xor(denom, 2);
    denom += __shfl_xor(denom, 4);

    float inv = 1.0f / (denom + 1e-16f);
    float4 b4 = *(const float4*)&bias[choff];
    union { uint2 u; __hip_bfloat162 b[2]; } p;
    p.b[0] = __float22bfloat162_rn(make_float2(acc.x * inv + b4.x, acc.y * inv + b4.y));
    p.b[1] = __float22bfloat162_rn(make_float2(acc.z * inv + b4.z, acc.w * inv + b4.w));
    *(uint2*)&out[(size_t)node * HID + choff] = p.u;
}

// ---------------- parallel mean pool (bf16 input) ----------------

#define POOL_CHUNK 64

__global__ __launch_bounds__(256) void pool_accum_kernel(const short* __restrict__ h,
                                                         const int* __restrict__ batch,
                                                         float* __restrict__ pooled,
                                                         int* __restrict__ cnt, int n) {
    int c0 = blockIdx.x * POOL_CHUNK;
    int c1 = c0 + POOL_CHUNK; if (c1 > n) c1 = n;
    int t = threadIdx.x;
    int g_cur = batch[c0];
    float acc = 0.f;
    int run = 0;
    for (int i = c0; i < c1; i++) {
        int g = batch[i];
        if (g != g_cur) {
            atomicAdd(&pooled[g_cur * HID + t], acc);
            if (t == 0) atomicAdd(&cnt[g_cur], run);
            acc = 0.f; run = 0; g_cur = g;
        }
        acc += bf2f(h[(size_t)i * HID + t]);
        run++;
    }
    atomicAdd(&pooled[g_cur * HID + t], acc);
    if (t == 0) atomicAdd(&cnt[g_cur], run);
}

// ---------------- final linear (with mean divide) ----------------

__global__ void final_kernel(const float* __restrict__ pooled, const int* __restrict__ cnt,
                             const float* __restrict__ W, const float* __restrict__ b,
                             float* __restrict__ out) {
    int idx = blockIdx.x * blockDim.x + threadIdx.x;
    if (idx >= NGRAPH * 10) return;
    int g = idx / 10, o = idx % 10;
    int c = cnt[g];
    float inv = 1.0f / (float)(c > 0 ? c : 1);
    float acc = b[o];
    for (int k = 0; k < HID; k++) acc += pooled[g * HID + k] * inv * W[k * 10 + o];
    out[idx] = acc;
}

extern "C" void kernel_launch(void* const* d_in, const int* in_sizes, int n_in,
                              void* d_out, int out_size, void* d_ws, size_t ws_size,
                              hipStream_t stream) {
    const float* x      = (const float*)d_in[0];
    const int*   ei     = (const int*)d_in[1];
    const int*   batch  = (const int*)d_in[2];
    const float* W0     = (const float*)d_in[3];
    const float* a_src0 = (const float*)d_in[4];
    const float* a_dst0 = (const float*)d_in[5];
    const float* b0     = (const float*)d_in[6];
    const float* Wh     = (const float*)d_in[7];   // [2,256,256]
    const float* a_srch = (const float*)d_in[8];   // [2,8,32]
    const float* a_dsth = (const float*)d_in[9];
    const float* bh     = (const float*)d_in[10];  // [2,256]
    const float* W_lin  = (const float*)d_in[11];
    const float* b_lin  = (const float*)d_in[12];
    float* out = (float*)d_out;

    // workspace carve-up (pooled..counts contiguous for single memset)
    // Wt sizes: 17 tiles x KC x 64 x 8 shorts; layer0 KC=4 -> 34816, layers1/2 KC=8 -> 69632
    short* hA     = (short*)d_ws;                    // 50000*256 bf16 (GEMM out)
    short* hB     = hA + (size_t)NN * HID;           // 50000*256 bf16 (att out)
    short* Wt0    = hB + (size_t)NN * HID;           // 34816 (17-tile swizzled)
    short* Wt1    = Wt0 + 17 * 4 * 64 * 8;           // 69632
    short* Wt2    = Wt1 + 17 * 8 * 64 * 8;           // 69632
    float* alS    = (float*)(Wt2 + 17 * 8 * 64 * 8);
    float* alD    = alS + (size_t)NN * HEADS;
    float* pooled = alD + (size_t)NN * HEADS;        // 128*256
    int* cnt      = (int*)(pooled + NGRAPH * HID);   // 128
    unsigned* gmaxA = (unsigned*)(cnt + NGRAPH);     // 24 (3 layers x 8 heads)
    int* counts   = (int*)(gmaxA + 24);              // 50000
    int* row_ptr  = counts + NN;                     // 50001
    int* cursor   = row_ptr + NN + 1;                // 50000
    int* srcs     = cursor + NN;                     // 850000
    int* partial  = srcs + (NE + NN);                // 64

    const int NEP = NE + NN;
    const int NB_SCAN = (NN + 1023) / 1024;          // 49 <= 64
    const int NB_CNT = (NE + 255) / 256;             // 3125

    // single zero-init: pooled + cnt + gmaxA + counts
    hipMemsetAsync(pooled, 0, (NGRAPH * HID + NGRAPH + 24 + NN) * sizeof(float), stream);

    // fused W-swizzle (+wa cols) + edge-count
    prep_kernel<<<816 + NB_CNT, 256, 0, stream>>>(W0, Wh, a_src0, a_dst0, a_srch, a_dsth,
                                                  Wt0, Wt1, Wt2, ei + NE, counts, NE);
    scan_part_kernel<<<NB_SCAN, 1024, 0, stream>>>(counts, partial, NN);
    scan_final_kernel<<<NB_SCAN, 1024, 0, stream>>>(counts, partial, row_ptr, cursor, NN);
    scatter_kernel<<<(NEP + 255) / 256, 256, 0, stream>>>(ei, cursor, srcs, NE, NN);

    const int gemm_grid = (NN + 127) / 128;          // 391 <= 512 resident: no tail
    const int agg_grid = (NN + 3) / 4;

    for (int l = 0; l < 3; l++) {
        const float* bb = (l == 0) ? b0 : bh + (size_t)(l - 1) * HID;
        unsigned* gm = gmaxA + l * 8;

        if (l == 0)
            gemm_mfma_kernel<128, true><<<gemm_grid, 256, 0, stream>>>(
                x, Wt0, hA, alS, alD, gm, NN);
        else
            gemm_mfma_kernel<256, false><<<gemm_grid, 256, 0, stream>>>(
                hB, (l == 1) ? Wt1 : Wt2, hA, alS, alD, gm, NN);
        att_fused_kernel<<<agg_grid, 256, 0, stream>>>(hA, alS, alD, gm, row_ptr, srcs, bb, hB, NN);
    }

    // pool + final linear
    pool_accum_kernel<<<(NN + POOL_CHUNK - 1) / POOL_CHUNK, 256, 0, stream>>>(hB, batch, pooled, cnt, NN);
    final_kernel<<<(NGRAPH * 10 + 255) / 256, 256, 0, stream>>>(pooled, cnt, W_lin, b_lin, out);
}